// Round 1
// baseline (1218.311 us; speedup 1.0000x reference)
//
#include <hip/hip_runtime.h>

#define WW 512   // image width/height
#define PP 8     // patch size
#define NN 4096  // patches per image (64*64)
#define BB 8     // batch
#define CC 128   // descriptor channels
#define SS 3     // weight-score channels

// ---------------------------------------------------------------------------
// Kernel 1: per-patch spatial softmax -> expected (u,v). One wave per patch.
// Lane l covers pixel (r=l/8, c=l%8) of its 8x8 patch.
// Writes coords to d_out and (u0, v0, wu, wv) bilinear prep to d_ws.
// ---------------------------------------------------------------------------
__global__ __launch_bounds__(256) void kp_softargmax(
    const float* __restrict__ det, float* __restrict__ coords,
    float4* __restrict__ aux)
{
    int gid  = blockIdx.x * 256 + threadIdx.x;
    int wave = gid >> 6;              // patch id in [0, BB*NN)
    int lane = threadIdx.x & 63;
    int b  = wave >> 12;              // / NN
    int n  = wave & (NN - 1);
    int py = n >> 6, px = n & 63;
    int r  = lane >> 3, c = lane & 7;
    int v  = py * PP + r;
    int u  = px * PP + c;

    float x = det[((size_t)b * WW + v) * WW + u];

    // 64-lane max reduction
    float m = x;
#pragma unroll
    for (int off = 32; off; off >>= 1)
        m = fmaxf(m, __shfl_xor(m, off));

    float e  = __expf(x - m);
    float sd = e;
    float su = e * (float)u;
    float sv = e * (float)v;
#pragma unroll
    for (int off = 32; off; off >>= 1) {
        sd += __shfl_xor(sd, off);
        su += __shfl_xor(su, off);
        sv += __shfl_xor(sv, off);
    }

    if (lane == 0) {
        float inv = 1.0f / sd;
        float eu  = su * inv;
        float ev  = sv * inv;
        size_t ci = ((size_t)b * NN + n) * 2;
        coords[ci]     = eu;
        coords[ci + 1] = ev;
        // bilinear prep: u0 = clip(floor(u), 0, W-2), wu = u - u0
        float u0 = fminf(fmaxf(floorf(eu), 0.0f), (float)(WW - 2));
        float v0 = fminf(fmaxf(floorf(ev), 0.0f), (float)(WW - 2));
        aux[(size_t)b * NN + n] = make_float4(u0, v0, eu - u0, ev - v0);
    }
}

// ---------------------------------------------------------------------------
// Kernel 2: bilinear gather for weight_scores (ch 0..2) and descriptors
// (ch 3..130). Thread = (b, ch, n); n fastest -> coalesced writes.
// ---------------------------------------------------------------------------
__global__ __launch_bounds__(256) void kp_gather(
    const float* __restrict__ wsc, const float* __restrict__ dsc,
    const float4* __restrict__ aux, float* __restrict__ out_scores,
    float* __restrict__ out_desc)
{
    int n  = blockIdx.x * 256 + threadIdx.x;   // 0..4095
    int ch = blockIdx.y;                        // 0..130
    int b  = blockIdx.z;                        // 0..7

    float4 a = aux[(size_t)b * NN + n];
    int   u0 = (int)a.x;
    int   v0 = (int)a.y;
    float wu = a.z;
    float wv = a.w;

    const float* img;
    float*       op;
    if (ch < SS) {
        img = wsc + ((size_t)b * SS + ch) * (WW * WW);
        op  = out_scores + ((size_t)b * SS + ch) * NN;
    } else {
        int c = ch - SS;
        img = dsc + ((size_t)b * CC + c) * (WW * WW);
        op  = out_desc + ((size_t)b * CC + c) * NN;
    }

    const float* p0 = img + (size_t)v0 * WW + u0;
    float f00 = p0[0],  f01 = p0[1];
    float f10 = p0[WW], f11 = p0[WW + 1];

    float top = f00 + wu * (f01 - f00);
    float bot = f10 + wu * (f11 - f10);
    op[n] = top + wv * (bot - top);
}

extern "C" void kernel_launch(void* const* d_in, const int* in_sizes, int n_in,
                              void* d_out, int out_size, void* d_ws, size_t ws_size,
                              hipStream_t stream) {
    const float* det = (const float*)d_in[0];  // (8,1,512,512)
    const float* wsc = (const float*)d_in[1];  // (8,3,512,512)
    const float* dsc = (const float*)d_in[2];  // (8,128,512,512)
    // d_in[3] = keypoint_masks: all-True, ignored (matches reference).

    float* out        = (float*)d_out;
    float* coords     = out;                                   // (8,4096,2)
    float* out_scores = out + (size_t)BB * NN * 2;             // (8,3,4096)
    float* out_desc   = out_scores + (size_t)BB * SS * NN;     // (8,128,4096)
    float4* aux       = (float4*)d_ws;                         // 32768 * 16 B

    // Kernel 1: 32768 patches, 4 waves per 256-thread block.
    kp_softargmax<<<dim3(BB * NN / 4), dim3(256), 0, stream>>>(det, coords, aux);

    // Kernel 2: grid (n-tiles, channels, batch).
    kp_gather<<<dim3(NN / 256, SS + CC, BB), dim3(256), 0, stream>>>(
        wsc, dsc, aux, out_scores, out_desc);
}